// Round 1
// baseline (371.029 us; speedup 1.0000x reference)
//
#include <hip/hip_runtime.h>
#include <hip/hip_bf16.h>

#define S_LEN 4096
#define E_DIM 512
#define D_DIM 64
#define H_NUM 8
#define LOG2E 1.4426950408889634f

typedef short bf16x8 __attribute__((ext_vector_type(8)));
typedef float f32x4 __attribute__((ext_vector_type(4)));
typedef unsigned short u16x8 __attribute__((ext_vector_type(8)));
typedef unsigned short u16x4 __attribute__((ext_vector_type(4)));

__device__ inline unsigned short f2bf(float x) {
    union { float f; unsigned u; } v; v.f = x;
    unsigned r = v.u + 0x7FFFu + ((v.u >> 16) & 1u);
    return (unsigned short)(r >> 16);
}
__device__ inline float bf2f(unsigned short b) {
    union { unsigned u; float f; } v; v.u = ((unsigned)b) << 16;
    return v.f;
}
__device__ inline f32x4 mfma16(bf16x8 a, bf16x8 b, f32x4 c) {
    return __builtin_amdgcn_mfma_f32_16x16x32_bf16(a, b, c, 0, 0, 0);
}

// ---------------------------------------------------------------------------
// Projection: for each head h and matrix z (0=Q,1=K,2=V):
//   P = X[4096,512] @ W[512,64]  (fp32 accumulate)
// Q,K written as split bf16 (hi = bf16(x), lo = bf16(x - hi)) in [H,S,D].
// V written as single bf16, TRANSPOSED [H,D,S] so flash staging is linear.
// ---------------------------------------------------------------------------
__global__ __launch_bounds__(256) void proj_kernel(
    const float* __restrict__ X, const float* __restrict__ Wq,
    const float* __restrict__ Wk, const float* __restrict__ Wv,
    unsigned short* __restrict__ Qhi, unsigned short* __restrict__ Qlo,
    unsigned short* __restrict__ Khi, unsigned short* __restrict__ Klo,
    unsigned short* __restrict__ Vt)
{
    __shared__ __align__(16) float Xs[32][128];   // [k][row], transposed
    __shared__ __align__(16) float Ws[32][64];    // [k][n]

    const int s0 = blockIdx.x * 128;
    const int h  = blockIdx.y;
    const int z  = blockIdx.z;
    const float* W = (z == 0 ? Wq : (z == 1 ? Wk : Wv)) + (size_t)h * E_DIM * D_DIM;

    const int tid = threadIdx.x;
    const int tx = tid & 15;        // col group: cols tx*4 .. tx*4+3
    const int ty = tid >> 4;        // row group: rows ty*8 .. ty*8+7

    float acc[8][4];
#pragma unroll
    for (int i = 0; i < 8; ++i)
#pragma unroll
        for (int j = 0; j < 4; ++j) acc[i][j] = 0.f;

    for (int kb = 0; kb < E_DIM; kb += 32) {
        __syncthreads();
        // stage X tile 128 rows x 32 k, transposed into Xs[k][row]
#pragma unroll
        for (int p = 0; p < 4; ++p) {
            int idx = tid + 256 * p;           // 0..1023
            int row = idx >> 3;
            int kq  = idx & 7;
            float4 xv = *(const float4*)&X[(size_t)(s0 + row) * E_DIM + kb + kq * 4];
            Xs[kq * 4 + 0][row] = xv.x;
            Xs[kq * 4 + 1][row] = xv.y;
            Xs[kq * 4 + 2][row] = xv.z;
            Xs[kq * 4 + 3][row] = xv.w;
        }
        // stage W tile 32 k x 64 n
#pragma unroll
        for (int p = 0; p < 2; ++p) {
            int idx = tid + 256 * p;           // 0..511
            int k  = idx >> 4;
            int nq = idx & 15;
            *(float4*)&Ws[k][nq * 4] = *(const float4*)&W[(size_t)(kb + k) * D_DIM + nq * 4];
        }
        __syncthreads();

#pragma unroll 8
        for (int k = 0; k < 32; ++k) {
            float a[8], b[4];
            *(float4*)&a[0] = *(const float4*)&Xs[k][ty * 8];
            *(float4*)&a[4] = *(const float4*)&Xs[k][ty * 8 + 4];
            *(float4*)&b[0] = *(const float4*)&Ws[k][tx * 4];
#pragma unroll
            for (int i = 0; i < 8; ++i)
#pragma unroll
                for (int j = 0; j < 4; ++j) acc[i][j] += a[i] * b[j];
        }
    }

    if (z < 2) {
        unsigned short* Ph = (z == 0) ? Qhi : Khi;
        unsigned short* Pl = (z == 0) ? Qlo : Klo;
#pragma unroll
        for (int i = 0; i < 8; ++i) {
            int s = s0 + ty * 8 + i;
            u16x4 hv, lv;
#pragma unroll
            for (int j = 0; j < 4; ++j) {
                float x = acc[i][j];
                unsigned short hb = f2bf(x);
                hv[j] = hb;
                lv[j] = f2bf(x - bf2f(hb));
            }
            size_t base = ((size_t)(h * S_LEN + s)) * D_DIM + tx * 4;
            *(u16x4*)&Ph[base] = hv;
            *(u16x4*)&Pl[base] = lv;
        }
    } else {
#pragma unroll
        for (int j = 0; j < 4; ++j) {
            u16x8 vv;
#pragma unroll
            for (int i = 0; i < 8; ++i) vv[i] = f2bf(acc[i][j]);
            size_t base = ((size_t)(h * D_DIM + tx * 4 + j)) * S_LEN + s0 + ty * 8;
            *(u16x8*)&Vt[base] = vv;
        }
    }
}

// ---------------------------------------------------------------------------
// Flash attention. Block = (1 head, 64 q-rows), 4 waves x 16 rows.
// K tiles (hi+lo) and V (transposed [D][keys]) staged in LDS with XOR swizzle.
// Scores = 3x bf16 MFMA (hi*hi + hi*lo + lo*hi) -> ~fp32-accurate.
// Online softmax in registers; P round-trips through per-wave LDS to get the
// MFMA A-fragment layout; PV accumulates fp32.
// Writes R[s][h*64+d] (concat-heads layout) in fp32.
// ---------------------------------------------------------------------------
__global__ __launch_bounds__(256) void flash_kernel(
    const unsigned short* __restrict__ Qhi, const unsigned short* __restrict__ Qlo,
    const unsigned short* __restrict__ Khi_g, const unsigned short* __restrict__ Klo_g,
    const unsigned short* __restrict__ Vt_g, float* __restrict__ R)
{
    __shared__ __align__(16) unsigned short KhiS[64 * 64];
    __shared__ __align__(16) unsigned short KloS[64 * 64];
    __shared__ __align__(16) unsigned short VtS[64 * 64];   // [d][key]
    __shared__ __align__(16) unsigned short PS[4][16 * 64]; // per-wave [row][key]

    const int h  = blockIdx.y;
    const int q0 = blockIdx.x * 64;
    const int tid  = threadIdx.x;
    const int lane = tid & 63;
    const int w    = tid >> 6;
    const int l15  = lane & 15;
    const int lhi  = lane >> 4;   // 0..3

    // Q fragments (A-operand): row = l15, d = lhi*8 + 32c + j
    const int qrow = q0 + w * 16 + l15;
    bf16x8 qh[2], ql[2];
#pragma unroll
    for (int c = 0; c < 2; ++c) {
        size_t off = ((size_t)(h * S_LEN + qrow)) * D_DIM + lhi * 8 + 32 * c;
        qh[c] = *(const bf16x8*)&Qhi[off];
        ql[c] = *(const bf16x8*)&Qlo[off];
    }

    f32x4 acc_o[4];
#pragma unroll
    for (int nt = 0; nt < 4; ++nt) acc_o[nt] = (f32x4){0.f, 0.f, 0.f, 0.f};
    float m[4], l[4];
#pragma unroll
    for (int r = 0; r < 4; ++r) { m[r] = -1e30f; l[r] = 0.f; }

    const int sr = tid >> 2;   // staging row 0..63
    const int sq = tid & 3;    // staging quarter (16 cols each)

    for (int kt = 0; kt < S_LEN / 64; ++kt) {
        __syncthreads();
        // ---- stage K hi/lo: row = key (64), col = d (64), swizzled
        {
            size_t gbase = ((size_t)(h * S_LEN + kt * 64 + sr)) * D_DIM + sq * 16;
#pragma unroll
            for (int half = 0; half < 2; ++half) {
                int colb = (sq * 16 + half * 8) * 2;
                int lo = sr * 128 + (((colb >> 4) ^ (sr & 7)) << 4);
                *(u16x8*)((char*)KhiS + lo) = *(const u16x8*)&Khi_g[gbase + half * 8];
                *(u16x8*)((char*)KloS + lo) = *(const u16x8*)&Klo_g[gbase + half * 8];
            }
        }
        // ---- stage Vt: row = d (64), col = key (64), swizzled
        {
            size_t gbase = ((size_t)(h * D_DIM + sr)) * S_LEN + kt * 64 + sq * 16;
#pragma unroll
            for (int half = 0; half < 2; ++half) {
                int colb = (sq * 16 + half * 8) * 2;
                int lo = sr * 128 + (((colb >> 4) ^ (sr & 7)) << 4);
                *(u16x8*)((char*)VtS + lo) = *(const u16x8*)&Vt_g[gbase + half * 8];
            }
        }
        __syncthreads();

        // ---- scores: S[16q x 64k] per wave, 3-term split MFMA
        f32x4 sacc[4];
#pragma unroll
        for (int nt = 0; nt < 4; ++nt) sacc[nt] = (f32x4){0.f, 0.f, 0.f, 0.f};
#pragma unroll
        for (int c = 0; c < 2; ++c) {
            int d0 = lhi * 8 + 32 * c;
            int colb = d0 * 2;
#pragma unroll
            for (int nt = 0; nt < 4; ++nt) {
                int key = l15 + 16 * nt;
                int lo = key * 128 + (((colb >> 4) ^ (key & 7)) << 4);
                bf16x8 kh = *(const bf16x8*)((const char*)KhiS + lo);
                bf16x8 kl = *(const bf16x8*)((const char*)KloS + lo);
                sacc[nt] = mfma16(qh[c], kh, sacc[nt]);
                sacc[nt] = mfma16(qh[c], kl, sacc[nt]);
                sacc[nt] = mfma16(ql[c], kh, sacc[nt]);
            }
        }

        // ---- online softmax (rows = lhi*4 + r; 16 lanes of same lhi hold a row)
        float p[4][4];
#pragma unroll
        for (int r = 0; r < 4; ++r) {
            float v = -1e30f;
#pragma unroll
            for (int nt = 0; nt < 4; ++nt) v = fmaxf(v, sacc[nt][r] * 0.125f);
#pragma unroll
            for (int off = 1; off < 16; off <<= 1) v = fmaxf(v, __shfl_xor(v, off));
            float mnew = fmaxf(m[r], v);
            float scale = exp2f((m[r] - mnew) * LOG2E);
            float sum = 0.f;
#pragma unroll
            for (int nt = 0; nt < 4; ++nt) {
                float pv = exp2f((sacc[nt][r] * 0.125f - mnew) * LOG2E);
                p[nt][r] = pv;
                sum += pv;
            }
#pragma unroll
            for (int off = 1; off < 16; off <<= 1) sum += __shfl_xor(sum, off);
            l[r] = l[r] * scale + sum;
            m[r] = mnew;
#pragma unroll
            for (int nt = 0; nt < 4; ++nt) acc_o[nt][r] *= scale;
        }

        // ---- P -> per-wave LDS (row = q-row 0..15, col = key, swizzled)
        unsigned short* pw = &PS[w][0];
#pragma unroll
        for (int nt = 0; nt < 4; ++nt) {
            int key = l15 + 16 * nt;
            int colb = key * 2;
#pragma unroll
            for (int r = 0; r < 4; ++r) {
                int row = lhi * 4 + r;
                int lo = row * 128 + (((colb >> 4) ^ (row & 7)) << 4) + (colb & 15);
                *(unsigned short*)((char*)pw + lo) = f2bf(p[nt][r]);
            }
        }

        // ---- PV: acc_o[16q x 64d] += P[16x64] @ V[64keys x 64d]
#pragma unroll
        for (int c = 0; c < 2; ++c) {
            int k0 = lhi * 8 + 32 * c;
            int colb = k0 * 2;
            int loA = l15 * 128 + (((colb >> 4) ^ (l15 & 7)) << 4);
            bf16x8 pa = *(const bf16x8*)((const char*)pw + loA);
#pragma unroll
            for (int nt = 0; nt < 4; ++nt) {
                int d = l15 + 16 * nt;
                int loB = d * 128 + (((colb >> 4) ^ (d & 7)) << 4);
                bf16x8 vb = *(const bf16x8*)((const char*)VtS + loB);
                acc_o[nt] = mfma16(pa, vb, acc_o[nt]);
            }
        }
    }

    // ---- epilogue: divide by l, write concat-heads R[s][h*64+d]
#pragma unroll
    for (int r = 0; r < 4; ++r) {
        float inv = 1.f / l[r];
        int s = q0 + w * 16 + lhi * 4 + r;
#pragma unroll
        for (int nt = 0; nt < 4; ++nt) {
            R[(size_t)s * (H_NUM * D_DIM) + h * D_DIM + l15 + 16 * nt] = acc_o[nt][r] * inv;
        }
    }
}

// ---------------------------------------------------------------------------
// Output projection: Z[4096,64] = R[4096,512] @ W0[512,64], fp32.
// ---------------------------------------------------------------------------
__global__ __launch_bounds__(256) void zout_kernel(
    const float* __restrict__ R, const float* __restrict__ W0, float* __restrict__ Z)
{
    __shared__ __align__(16) float Rs[32][64];   // [k][row]
    __shared__ __align__(16) float Ws[32][64];   // [k][n]

    const int s0 = blockIdx.x * 64;
    const int tid = threadIdx.x;
    const int tx = tid & 15;    // cols tx*4..+3
    const int ty = tid >> 4;    // rows ty*4..+3

    float acc[4][4];
#pragma unroll
    for (int i = 0; i < 4; ++i)
#pragma unroll
        for (int j = 0; j < 4; ++j) acc[i][j] = 0.f;

    for (int kb = 0; kb < E_DIM; kb += 32) {
        __syncthreads();
#pragma unroll
        for (int p = 0; p < 2; ++p) {
            int idx = tid + 256 * p;          // 0..511
            int row = idx >> 3;
            int kq  = idx & 7;
            float4 xv = *(const float4*)&R[(size_t)(s0 + row) * E_DIM + kb + kq * 4];
            Rs[kq * 4 + 0][row] = xv.x;
            Rs[kq * 4 + 1][row] = xv.y;
            Rs[kq * 4 + 2][row] = xv.z;
            Rs[kq * 4 + 3][row] = xv.w;
        }
#pragma unroll
        for (int p = 0; p < 2; ++p) {
            int idx = tid + 256 * p;
            int k  = idx >> 4;
            int nq = idx & 15;
            *(float4*)&Ws[k][nq * 4] = *(const float4*)&W0[(size_t)(kb + k) * D_DIM + nq * 4];
        }
        __syncthreads();

#pragma unroll 8
        for (int k = 0; k < 32; ++k) {
            float a[4], b[4];
            *(float4*)&a[0] = *(const float4*)&Rs[k][ty * 4];
            *(float4*)&b[0] = *(const float4*)&Ws[k][tx * 4];
#pragma unroll
            for (int i = 0; i < 4; ++i)
#pragma unroll
                for (int j = 0; j < 4; ++j) acc[i][j] += a[i] * b[j];
        }
    }

#pragma unroll
    for (int i = 0; i < 4; ++i) {
        float4 o = make_float4(acc[i][0], acc[i][1], acc[i][2], acc[i][3]);
        *(float4*)&Z[(size_t)(s0 + ty * 4 + i) * D_DIM + tx * 4] = o;
    }
}

// ---------------------------------------------------------------------------
extern "C" void kernel_launch(void* const* d_in, const int* in_sizes, int n_in,
                              void* d_out, int out_size, void* d_ws, size_t ws_size,
                              hipStream_t stream) {
    const float* X  = (const float*)d_in[0];
    const float* Wq = (const float*)d_in[1];
    const float* Wk = (const float*)d_in[2];
    const float* Wv = (const float*)d_in[3];
    const float* W0 = (const float*)d_in[4];

    char* ws = (char*)d_ws;
    const size_t SZ_BF = (size_t)H_NUM * S_LEN * D_DIM * sizeof(unsigned short); // 4 MB
    unsigned short* Qhi = (unsigned short*)(ws + 0 * SZ_BF);
    unsigned short* Qlo = (unsigned short*)(ws + 1 * SZ_BF);
    unsigned short* Khi = (unsigned short*)(ws + 2 * SZ_BF);
    unsigned short* Klo = (unsigned short*)(ws + 3 * SZ_BF);
    unsigned short* Vt  = (unsigned short*)(ws + 4 * SZ_BF);
    float* R = (float*)(ws + 5 * SZ_BF);                                          // 8 MB

    float* Z = (float*)d_out;

    proj_kernel<<<dim3(S_LEN / 128, H_NUM, 3), 256, 0, stream>>>(
        X, Wq, Wk, Wv, Qhi, Qlo, Khi, Klo, Vt);
    flash_kernel<<<dim3(S_LEN / 64, H_NUM), 256, 0, stream>>>(
        Qhi, Qlo, Khi, Klo, Vt, R);
    zout_kernel<<<dim3(S_LEN / 64), 256, 0, stream>>>(R, W0, Z);
}

// Round 2
// 295.666 us; speedup vs baseline: 1.2549x; 1.2549x over previous
//
#include <hip/hip_runtime.h>
#include <hip/hip_bf16.h>

#define S_LEN 4096
#define E_DIM 512
#define D_DIM 64
#define H_NUM 8
// scale = 1/sqrt(64) * log2(e): scores come out of MFMA already in exp2 domain
#define QSCALE 0.18033688011112042f

typedef short bf16x8 __attribute__((ext_vector_type(8)));
typedef float f32x4 __attribute__((ext_vector_type(4)));
typedef unsigned short u16x8 __attribute__((ext_vector_type(8)));
typedef unsigned short u16x4 __attribute__((ext_vector_type(4)));

__device__ inline unsigned short f2bf(float x) {
    union { float f; unsigned u; } v; v.f = x;
    unsigned r = v.u + 0x7FFFu + ((v.u >> 16) & 1u);
    return (unsigned short)(r >> 16);
}
__device__ inline float bf2f(unsigned short b) {
    union { unsigned u; float f; } v; v.u = ((unsigned)b) << 16;
    return v.f;
}
__device__ inline f32x4 mfma16(bf16x8 a, bf16x8 b, f32x4 c) {
    return __builtin_amdgcn_mfma_f32_16x16x32_bf16(a, b, c, 0, 0, 0);
}
__device__ inline void gl_lds16(const void* g, void* l) {
    __builtin_amdgcn_global_load_lds(
        (const __attribute__((address_space(1))) void*)g,
        (__attribute__((address_space(3))) void*)l, 16, 0, 0);
}

// ---------------------------------------------------------------------------
// prepass_x: X fp32 [4096,512] -> Xhi,Xlo bf16 (hi/lo split)
// ---------------------------------------------------------------------------
__global__ __launch_bounds__(256) void prepass_x(
    const float* __restrict__ X, unsigned short* __restrict__ Xhi,
    unsigned short* __restrict__ Xlo)
{
    int i = (blockIdx.x * 256 + threadIdx.x) * 4;
    float4 v = *(const float4*)&X[i];
    float a[4] = {v.x, v.y, v.z, v.w};
    u16x4 hv, lv;
#pragma unroll
    for (int j = 0; j < 4; ++j) {
        unsigned short hb = f2bf(a[j]);
        hv[j] = hb;
        lv[j] = f2bf(a[j] - bf2f(hb));
    }
    *(u16x4*)&Xhi[i] = hv;
    *(u16x4*)&Xlo[i] = lv;
}

// ---------------------------------------------------------------------------
// prepass_w: W_z [H,E,D] fp32 -> WT[z][hl][n=h*64+d][e] bf16 hi/lo (transposed)
// ---------------------------------------------------------------------------
__global__ __launch_bounds__(256) void prepass_w(
    const float* __restrict__ Wq, const float* __restrict__ Wk,
    const float* __restrict__ Wv, unsigned short* __restrict__ WT)
{
    int z = blockIdx.y;
    const float* W = (z == 0) ? Wq : (z == 1) ? Wk : Wv;
    int idx = blockIdx.x * 256 + threadIdx.x;        // 512*128
    int n = idx >> 7;
    int e = (idx & 127) * 4;
    int hh = n >> 6, d = n & 63;
    unsigned short* Whi = WT + (size_t)z * 2 * 262144;
    unsigned short* Wlo = Whi + 262144;
    u16x4 hv, lv;
#pragma unroll
    for (int j = 0; j < 4; ++j) {
        float v = W[((size_t)hh * E_DIM + e + j) * D_DIM + d];
        unsigned short hb = f2bf(v);
        hv[j] = hb;
        lv[j] = f2bf(v - bf2f(hb));
    }
    *(u16x4*)&Whi[(size_t)n * E_DIM + e] = hv;
    *(u16x4*)&Wlo[(size_t)n * E_DIM + e] = lv;
}

// ---------------------------------------------------------------------------
// proj: C[4096,512] = X @ Wcat  per z, 3-term split-bf16 MFMA (fp32-accurate).
// 128x128 tile, 4 waves (2x2), K-step 64, global_load_lds w/ pre-swizzled src.
// z=0 -> Qhi/Qlo (pre-scaled by QSCALE), z=1 -> Khi/Klo, z=2 -> Vb bf16.
// ---------------------------------------------------------------------------
__global__ __launch_bounds__(256) void proj_kernel(
    const unsigned short* __restrict__ Xhi, const unsigned short* __restrict__ Xlo,
    const unsigned short* __restrict__ WT,
    unsigned short* __restrict__ Qhi, unsigned short* __restrict__ Qlo,
    unsigned short* __restrict__ Khi, unsigned short* __restrict__ Klo,
    unsigned short* __restrict__ Vb)
{
    __shared__ __align__(16) unsigned short XhS[128 * 64];
    __shared__ __align__(16) unsigned short XlS[128 * 64];
    __shared__ __align__(16) unsigned short WhS[128 * 64];
    __shared__ __align__(16) unsigned short WlS[128 * 64];

    const int s0 = blockIdx.x * 128, n0 = blockIdx.y * 128, z = blockIdx.z;
    const unsigned short* Wh_g = WT + (size_t)z * 524288;
    const unsigned short* Wl_g = Wh_g + 262144;

    const int tid = threadIdx.x, lane = tid & 63, w = tid >> 6;
    const int l15 = lane & 15, lhi = lane >> 4;
    const int wr = w >> 1, wc = w & 1;

    const int chunk = lane & 7;
    size_t aoff[4], boff[4];
    int ldso[4];
#pragma unroll
    for (int i = 0; i < 4; ++i) {
        int r = w * 32 + i * 8 + (lane >> 3);
        int swz = (chunk * 16) ^ ((r & 7) << 4);
        aoff[i] = ((size_t)(s0 + r)) * 1024 + swz;   // bytes (row stride 512*2)
        boff[i] = ((size_t)(n0 + r)) * 1024 + swz;
        ldso[i] = (w * 32 + i * 8) * 128;            // bytes, wave-uniform
    }

    f32x4 acc[4][4];
#pragma unroll
    for (int a = 0; a < 4; ++a)
#pragma unroll
        for (int b = 0; b < 4; ++b) acc[a][b] = (f32x4){0.f, 0.f, 0.f, 0.f};

    for (int kb = 0; kb < E_DIM; kb += 64) {
        __syncthreads();
#pragma unroll
        for (int i = 0; i < 4; ++i) {
            size_t ab = aoff[i] + kb * 2;
            size_t bb = boff[i] + kb * 2;
            gl_lds16((const char*)Xhi + ab, (char*)XhS + ldso[i]);
            gl_lds16((const char*)Xlo + ab, (char*)XlS + ldso[i]);
            gl_lds16((const char*)Wh_g + bb, (char*)WhS + ldso[i]);
            gl_lds16((const char*)Wl_g + bb, (char*)WlS + ldso[i]);
        }
        __syncthreads();

#pragma unroll
        for (int kc = 0; kc < 2; ++kc) {
            int cb = kc * 64 + lhi * 16;
            bf16x8 ah[4], al[4], bh[4], bl[4];
#pragma unroll
            for (int rt = 0; rt < 4; ++rt) {
                int row = wr * 64 + rt * 16 + l15;
                int ad = row * 128 + (cb ^ ((row & 7) << 4));
                ah[rt] = *(const bf16x8*)((const char*)XhS + ad);
                al[rt] = *(const bf16x8*)((const char*)XlS + ad);
            }
#pragma unroll
            for (int nt = 0; nt < 4; ++nt) {
                int n = wc * 64 + nt * 16 + l15;
                int bd = n * 128 + (cb ^ ((n & 7) << 4));
                bh[nt] = *(const bf16x8*)((const char*)WhS + bd);
                bl[nt] = *(const bf16x8*)((const char*)WlS + bd);
            }
#pragma unroll
            for (int rt = 0; rt < 4; ++rt)
#pragma unroll
                for (int nt = 0; nt < 4; ++nt) {
                    acc[rt][nt] = mfma16(ah[rt], bh[nt], acc[rt][nt]);
                    acc[rt][nt] = mfma16(ah[rt], bl[nt], acc[rt][nt]);
                    acc[rt][nt] = mfma16(al[rt], bh[nt], acc[rt][nt]);
                }
        }
    }

    // epilogue: C/D layout col=l15, row=lhi*4+j
#pragma unroll
    for (int rt = 0; rt < 4; ++rt)
#pragma unroll
        for (int nt = 0; nt < 4; ++nt) {
            int n = n0 + wc * 64 + nt * 16 + l15;
            int hh = n >> 6, d = n & 63;
#pragma unroll
            for (int j = 0; j < 4; ++j) {
                int s = s0 + wr * 64 + rt * 16 + lhi * 4 + j;
                float val = acc[rt][nt][j];
                size_t o = ((size_t)hh * S_LEN + s) * D_DIM + d;
                if (z == 0) {
                    val *= QSCALE;
                    unsigned short hb = f2bf(val);
                    Qhi[o] = hb;
                    Qlo[o] = f2bf(val - bf2f(hb));
                } else if (z == 1) {
                    unsigned short hb = f2bf(val);
                    Khi[o] = hb;
                    Klo[o] = f2bf(val - bf2f(hb));
                } else {
                    Vb[o] = f2bf(val);
                }
            }
        }
}

// ---------------------------------------------------------------------------
// pack_vt: Vb [h][s][d] bf16 -> Vt [h][d][s] bf16 (LDS tiled transpose)
// ---------------------------------------------------------------------------
__global__ __launch_bounds__(256) void pack_vt(
    const unsigned short* __restrict__ Vb, unsigned short* __restrict__ Vt)
{
    __shared__ unsigned short T[64][72];
    int h = blockIdx.y, sblk = blockIdx.x * 64;
    int t = threadIdx.x;
#pragma unroll
    for (int p = 0; p < 2; ++p) {
        int slot = t + 256 * p;          // 0..511
        int s = slot >> 3, c = slot & 7;
        u16x8 v = *(const u16x8*)&Vb[((size_t)h * S_LEN + sblk + s) * D_DIM + c * 8];
#pragma unroll
        for (int j = 0; j < 8; ++j) T[c * 8 + j][s] = v[j];
    }
    __syncthreads();
#pragma unroll
    for (int p = 0; p < 2; ++p) {
        int slot = t + 256 * p;
        int d = slot >> 3, c = slot & 7;
        u16x8 v;
#pragma unroll
        for (int j = 0; j < 8; ++j) v[j] = T[d][c * 8 + j];
        *(u16x8*)&Vt[((size_t)(h * D_DIM + d)) * S_LEN + sblk + c * 8] = v;
    }
}

// ---------------------------------------------------------------------------
// flash: K-split=2. Block = (head, 64 q-rows, ks). 4 waves x 16 rows.
// Staging via global_load_lds (pre-swizzled source). Scores already in exp2
// domain (Q pre-scaled). T13 defer-rescale (THR=8). Writes normalized bf16
// partials + (m,l) per row.
// ---------------------------------------------------------------------------
__global__ __launch_bounds__(256, 4) void flash_kernel(
    const unsigned short* __restrict__ Qhi, const unsigned short* __restrict__ Qlo,
    const unsigned short* __restrict__ Khi_g, const unsigned short* __restrict__ Klo_g,
    const unsigned short* __restrict__ Vt_g,
    unsigned short* __restrict__ Part, float2* __restrict__ ML)
{
    __shared__ __align__(16) unsigned short KhiS[64 * 64];
    __shared__ __align__(16) unsigned short KloS[64 * 64];
    __shared__ __align__(16) unsigned short VtS[64 * 64];   // [d][key]
    __shared__ __align__(16) unsigned short PS[4][16 * 64]; // per-wave [row][key]

    const int h  = blockIdx.y;
    const int ks = blockIdx.z;
    const int q0 = blockIdx.x * 64;
    const int tid  = threadIdx.x;
    const int lane = tid & 63;
    const int w    = tid >> 6;
    const int l15  = lane & 15;
    const int lhi  = lane >> 4;

    // Q fragments (A-operand): row = l15, d = lhi*8 + 32c + j
    const int qrow = q0 + w * 16 + l15;
    bf16x8 qh[2], ql[2];
#pragma unroll
    for (int c = 0; c < 2; ++c) {
        size_t off = ((size_t)(h * S_LEN + qrow)) * D_DIM + lhi * 8 + 32 * c;
        qh[c] = *(const bf16x8*)&Qhi[off];
        ql[c] = *(const bf16x8*)&Qlo[off];
    }

    // staging source pointers (pre-swizzled within 128B rows)
    const char *pKh[2], *pKl[2], *pV[2];
    int ldsd[2];
    {
        const int chunk = lane & 7;
#pragma unroll
        for (int i = 0; i < 2; ++i) {
            int r = w * 16 + i * 8 + (lane >> 3);
            int swz = (chunk * 16) ^ ((r & 7) << 4);
            size_t kb = ((size_t)(h * S_LEN + ks * 2048 + r)) * 128 + swz;
            pKh[i] = (const char*)Khi_g + kb;
            pKl[i] = (const char*)Klo_g + kb;
            size_t vb = ((size_t)(h * D_DIM + r) * S_LEN + ks * 2048) * 2 + swz;
            pV[i] = (const char*)Vt_g + vb;
            ldsd[i] = (w * 16 + i * 8) * 128;
        }
    }

    f32x4 acc_o[4];
#pragma unroll
    for (int nt = 0; nt < 4; ++nt) acc_o[nt] = (f32x4){0.f, 0.f, 0.f, 0.f};
    float m2[4], l[4];
#pragma unroll
    for (int r = 0; r < 4; ++r) { m2[r] = -1e30f; l[r] = 0.f; }

    for (int kt = 0; kt < 32; ++kt) {
        __syncthreads();
#pragma unroll
        for (int i = 0; i < 2; ++i) {
            gl_lds16(pKh[i], (char*)KhiS + ldsd[i]);
            gl_lds16(pKl[i], (char*)KloS + ldsd[i]);
            gl_lds16(pV[i],  (char*)VtS  + ldsd[i]);
            pKh[i] += 8192; pKl[i] += 8192; pV[i] += 128;
        }
        __syncthreads();

        // ---- scores (exp2 domain): 3-term split MFMA
        f32x4 sacc[4];
#pragma unroll
        for (int nt = 0; nt < 4; ++nt) sacc[nt] = (f32x4){0.f, 0.f, 0.f, 0.f};
#pragma unroll
        for (int c = 0; c < 2; ++c) {
            int colb = (lhi * 8 + 32 * c) * 2;
#pragma unroll
            for (int nt = 0; nt < 4; ++nt) {
                int key = l15 + 16 * nt;
                int lo = key * 128 + (((colb >> 4) ^ (key & 7)) << 4);
                bf16x8 kh = *(const bf16x8*)((const char*)KhiS + lo);
                bf16x8 kl = *(const bf16x8*)((const char*)KloS + lo);
                sacc[nt] = mfma16(qh[c], kh, sacc[nt]);
                sacc[nt] = mfma16(qh[c], kl, sacc[nt]);
                sacc[nt] = mfma16(ql[c], kh, sacc[nt]);
            }
        }

        // ---- online softmax, T13 defer-rescale (p bounded by 2^8)
        float p[4][4];
#pragma unroll
        for (int r = 0; r < 4; ++r) {
            float vm = fmaxf(fmaxf(sacc[0][r], sacc[1][r]), fmaxf(sacc[2][r], sacc[3][r]));
#pragma unroll
            for (int off = 1; off < 16; off <<= 1) vm = fmaxf(vm, __shfl_xor(vm, off));
            if (vm > m2[r] + 8.f) {
                float sc = exp2f(m2[r] - vm);
                m2[r] = vm;
                l[r] *= sc;
#pragma unroll
                for (int nt = 0; nt < 4; ++nt) acc_o[nt][r] *= sc;
            }
            float sum = 0.f;
#pragma unroll
            for (int nt = 0; nt < 4; ++nt) {
                float pv = exp2f(sacc[nt][r] - m2[r]);
                p[nt][r] = pv;
                sum += pv;
            }
#pragma unroll
            for (int off = 1; off < 16; off <<= 1) sum += __shfl_xor(sum, off);
            l[r] += sum;
        }

        // ---- P -> per-wave LDS (row = q-row 0..15, col = key, swizzled)
        unsigned short* pw = &PS[w][0];
#pragma unroll
        for (int nt = 0; nt < 4; ++nt) {
            int colb = (l15 + 16 * nt) * 2;
#pragma unroll
            for (int r = 0; r < 4; ++r) {
                int row = lhi * 4 + r;
                int lo = row * 128 + (((colb >> 4) ^ (row & 7)) << 4) + (colb & 15);
                *(unsigned short*)((char*)pw + lo) = f2bf(p[nt][r]);
            }
        }

        // ---- PV
#pragma unroll
        for (int c = 0; c < 2; ++c) {
            int colb = (lhi * 8 + 32 * c) * 2;
            int loA = l15 * 128 + (((colb >> 4) ^ (l15 & 7)) << 4);
            bf16x8 pa = *(const bf16x8*)((const char*)pw + loA);
#pragma unroll
            for (int nt = 0; nt < 4; ++nt) {
                int d = l15 + 16 * nt;
                int loB = d * 128 + (((colb >> 4) ^ (d & 7)) << 4);
                bf16x8 vb = *(const bf16x8*)((const char*)VtS + loB);
                acc_o[nt] = mfma16(pa, vb, acc_o[nt]);
            }
        }
    }

    // ---- epilogue: normalized bf16 partial + (m,l)
    unsigned short* PT = Part + ((size_t)(ks * H_NUM + h)) * S_LEN * D_DIM;
#pragma unroll
    for (int r = 0; r < 4; ++r) {
        float inv = 1.f / l[r];
        int s = q0 + w * 16 + lhi * 4 + r;
#pragma unroll
        for (int nt = 0; nt < 4; ++nt)
            PT[(size_t)s * D_DIM + l15 + 16 * nt] = f2bf(acc_o[nt][r] * inv);
        if (l15 == 0)
            ML[(size_t)(ks * H_NUM + h) * S_LEN + s] = make_float2(m2[r], l[r]);
    }
}

// ---------------------------------------------------------------------------
// cw: per (h,s) combine weights c_i = l_i*2^(m_i-m) / L
// ---------------------------------------------------------------------------
__global__ __launch_bounds__(256) void cw_kernel(
    const float2* __restrict__ ML, float2* __restrict__ CW)
{
    int i = blockIdx.x * 256 + threadIdx.x;   // 32768
    float2 a = ML[i];
    float2 b = ML[H_NUM * S_LEN + i];
    float m = fmaxf(a.x, b.x);
    float w1 = exp2f(a.x - m) * a.y;
    float w2 = exp2f(b.x - m) * b.y;
    float inv = 1.f / (w1 + w2);
    CW[i] = make_float2(w1 * inv, w2 * inv);
}

// ---------------------------------------------------------------------------
// zout: Z[4096,64] = combine(Part1,Part2) [4096,512] @ W0[512,64], fp32.
// ---------------------------------------------------------------------------
__global__ __launch_bounds__(256) void zout_kernel(
    const unsigned short* __restrict__ Part, const float2* __restrict__ CW,
    const float* __restrict__ W0, float* __restrict__ Z)
{
    __shared__ __align__(16) float Rs[32][64];   // [k][row]
    __shared__ __align__(16) float Ws[32][64];   // [k][n]

    const unsigned short* P1 = Part;
    const unsigned short* P2 = Part + (size_t)H_NUM * S_LEN * D_DIM;

    const int s0 = blockIdx.x * 64;
    const int tid = threadIdx.x;
    const int tx = tid & 15;
    const int ty = tid >> 4;

    float acc[4][4];
#pragma unroll
    for (int i = 0; i < 4; ++i)
#pragma unroll
        for (int j = 0; j < 4; ++j) acc[i][j] = 0.f;

    for (int kb = 0; kb < E_DIM; kb += 32) {
        __syncthreads();
#pragma unroll
        for (int p = 0; p < 2; ++p) {
            int idx = tid + 256 * p;          // 0..511
            int row = idx >> 3;
            int kq  = idx & 7;
            int k = kb + kq * 4;
            int hh = k >> 6, d0 = k & 63;
            int s = s0 + row;
            size_t pbase = ((size_t)hh * S_LEN + s) * D_DIM + d0;
            u16x4 a1 = *(const u16x4*)&P1[pbase];
            u16x4 a2 = *(const u16x4*)&P2[pbase];
            float2 c = CW[hh * S_LEN + s];
#pragma unroll
            for (int j = 0; j < 4; ++j)
                Rs[kq * 4 + j][row] = bf2f(a1[j]) * c.x + bf2f(a2[j]) * c.y;
        }
#pragma unroll
        for (int p = 0; p < 2; ++p) {
            int idx = tid + 256 * p;
            int k  = idx >> 4;
            int nq = idx & 15;
            *(float4*)&Ws[k][nq * 4] = *(const float4*)&W0[(size_t)(kb + k) * D_DIM + nq * 4];
        }
        __syncthreads();

#pragma unroll 8
        for (int k = 0; k < 32; ++k) {
            float a[4], b[4];
            *(float4*)&a[0] = *(const float4*)&Rs[k][ty * 4];
            *(float4*)&b[0] = *(const float4*)&Ws[k][tx * 4];
#pragma unroll
            for (int i = 0; i < 4; ++i)
#pragma unroll
                for (int j = 0; j < 4; ++j) acc[i][j] += a[i] * b[j];
        }
    }

#pragma unroll
    for (int i = 0; i < 4; ++i) {
        float4 o = make_float4(acc[i][0], acc[i][1], acc[i][2], acc[i][3]);
        *(float4*)&Z[(size_t)(s0 + ty * 4 + i) * D_DIM + tx * 4] = o;
    }
}

// ---------------------------------------------------------------------------
extern "C" void kernel_launch(void* const* d_in, const int* in_sizes, int n_in,
                              void* d_out, int out_size, void* d_ws, size_t ws_size,
                              hipStream_t stream) {
    const float* X  = (const float*)d_in[0];
    const float* Wq = (const float*)d_in[1];
    const float* Wk = (const float*)d_in[2];
    const float* Wv = (const float*)d_in[3];
    const float* W0 = (const float*)d_in[4];

    char* ws = (char*)d_ws;
    const size_t MB = 1ull << 20;
    unsigned short* Qhi = (unsigned short*)(ws + 0 * MB);
    unsigned short* Qlo = (unsigned short*)(ws + 4 * MB);
    unsigned short* Khi = (unsigned short*)(ws + 8 * MB);
    unsigned short* Klo = (unsigned short*)(ws + 12 * MB);
    unsigned short* Vt  = (unsigned short*)(ws + 16 * MB);
    unsigned short* Vb  = (unsigned short*)(ws + 20 * MB);
    // region R1: phase 1 (prepass -> proj)
    unsigned short* Xhi = (unsigned short*)(ws + 24 * MB);
    unsigned short* Xlo = (unsigned short*)(ws + 28 * MB);
    unsigned short* WT  = (unsigned short*)(ws + 32 * MB);   // 3 MB
    // region R1: phase 2 (flash -> zout), aliases Xhi/Xlo and WT
    unsigned short* Part = (unsigned short*)(ws + 24 * MB);  // 8 MB (2 splits)
    float2* ML = (float2*)(ws + 32 * MB);                    // 512 KB
    float2* CW = (float2*)(ws + 32 * MB + 512 * 1024);       // 256 KB

    float* Z = (float*)d_out;

    prepass_x<<<dim3(S_LEN * E_DIM / 4 / 256), 256, 0, stream>>>(X, Xhi, Xlo);
    prepass_w<<<dim3(E_DIM * 128 / 256, 3), 256, 0, stream>>>(Wq, Wk, Wv, WT);
    proj_kernel<<<dim3(S_LEN / 128, 4, 3), 256, 0, stream>>>(
        Xhi, Xlo, WT, Qhi, Qlo, Khi, Klo, Vb);
    pack_vt<<<dim3(S_LEN / 64, H_NUM), 256, 0, stream>>>(Vb, Vt);
    flash_kernel<<<dim3(S_LEN / 64, H_NUM, 2), 256, 0, stream>>>(
        Qhi, Qlo, Khi, Klo, Vt, Part, ML);
    cw_kernel<<<dim3(H_NUM * S_LEN / 256), 256, 0, stream>>>(ML, CW);
    zout_kernel<<<dim3(S_LEN / 64), 256, 0, stream>>>(Part, CW, W0, Z);
}

// Round 5
// 279.937 us; speedup vs baseline: 1.3254x; 1.0562x over previous
//
#include <hip/hip_runtime.h>
#include <hip/hip_bf16.h>

#define S_LEN 4096
#define E_DIM 512
#define D_DIM 64
#define H_NUM 8
#define KSPLIT 4
#define NKT ((S_LEN / KSPLIT) / 64)   // 16 key tiles per flash block
// scale = 1/sqrt(64) * log2(e): scores come out of MFMA already in exp2 domain
#define QSCALE 0.18033688011112042f

typedef short bf16x8 __attribute__((ext_vector_type(8)));
typedef float f32x4 __attribute__((ext_vector_type(4)));
typedef unsigned short u16x8 __attribute__((ext_vector_type(8)));
typedef unsigned short u16x4 __attribute__((ext_vector_type(4)));

__device__ inline unsigned short f2bf(float x) {
    union { float f; unsigned u; } v; v.f = x;
    unsigned r = v.u + 0x7FFFu + ((v.u >> 16) & 1u);
    return (unsigned short)(r >> 16);
}
__device__ inline float bf2f(unsigned short b) {
    union { unsigned u; float f; } v; v.u = ((unsigned)b) << 16;
    return v.f;
}
__device__ inline f32x4 mfma16(bf16x8 a, bf16x8 b, f32x4 c) {
    return __builtin_amdgcn_mfma_f32_16x16x32_bf16(a, b, c, 0, 0, 0);
}
__device__ inline void gl_lds16(const void* g, void* l) {
    __builtin_amdgcn_global_load_lds(
        (const __attribute__((address_space(1))) void*)g,
        (__attribute__((address_space(3))) void*)l, 16, 0, 0);
}

// ---------------------------------------------------------------------------
// prepass_x: X fp32 [4096,512] -> Xhi,Xlo bf16 (hi/lo split)
// ---------------------------------------------------------------------------
__global__ __launch_bounds__(256) void prepass_x(
    const float* __restrict__ X, unsigned short* __restrict__ Xhi,
    unsigned short* __restrict__ Xlo)
{
    int i = (blockIdx.x * 256 + threadIdx.x) * 4;
    float4 v = *(const float4*)&X[i];
    float a[4] = {v.x, v.y, v.z, v.w};
    u16x4 hv, lv;
#pragma unroll
    for (int j = 0; j < 4; ++j) {
        unsigned short hb = f2bf(a[j]);
        hv[j] = hb;
        lv[j] = f2bf(a[j] - bf2f(hb));
    }
    *(u16x4*)&Xhi[i] = hv;
    *(u16x4*)&Xlo[i] = lv;
}

// ---------------------------------------------------------------------------
// prepass_w: W_z [H,E,D] fp32 -> WT[z][hl][n=h*64+d][e] bf16 hi/lo (transposed)
// ---------------------------------------------------------------------------
__global__ __launch_bounds__(256) void prepass_w(
    const float* __restrict__ Wq, const float* __restrict__ Wk,
    const float* __restrict__ Wv, unsigned short* __restrict__ WT)
{
    int z = blockIdx.y;
    const float* W = (z == 0) ? Wq : (z == 1) ? Wk : Wv;
    int idx = blockIdx.x * 256 + threadIdx.x;        // 512*128
    int n = idx >> 7;
    int e = (idx & 127) * 4;
    int hh = n >> 6, d = n & 63;
    unsigned short* Whi = WT + (size_t)z * 2 * 262144;
    unsigned short* Wlo = Whi + 262144;
    u16x4 hv, lv;
#pragma unroll
    for (int j = 0; j < 4; ++j) {
        float v = W[((size_t)hh * E_DIM + e + j) * D_DIM + d];
        unsigned short hb = f2bf(v);
        hv[j] = hb;
        lv[j] = f2bf(v - bf2f(hb));
    }
    *(u16x4*)&Whi[(size_t)n * E_DIM + e] = hv;
    *(u16x4*)&Wlo[(size_t)n * E_DIM + e] = lv;
}

// ---------------------------------------------------------------------------
// proj: C[4096,512] = X @ Wcat per z, 3-term split-bf16 MFMA (fp32-accurate).
// ---------------------------------------------------------------------------
__global__ __launch_bounds__(256) void proj_kernel(
    const unsigned short* __restrict__ Xhi, const unsigned short* __restrict__ Xlo,
    const unsigned short* __restrict__ WT,
    unsigned short* __restrict__ Qhi, unsigned short* __restrict__ Qlo,
    unsigned short* __restrict__ Khi, unsigned short* __restrict__ Klo,
    unsigned short* __restrict__ Vb)
{
    __shared__ __align__(16) unsigned short XhS[128 * 64];
    __shared__ __align__(16) unsigned short XlS[128 * 64];
    __shared__ __align__(16) unsigned short WhS[128 * 64];
    __shared__ __align__(16) unsigned short WlS[128 * 64];

    const int s0 = blockIdx.x * 128, n0 = blockIdx.y * 128, z = blockIdx.z;
    const unsigned short* Wh_g = WT + (size_t)z * 524288;
    const unsigned short* Wl_g = Wh_g + 262144;

    const int tid = threadIdx.x, lane = tid & 63, w = tid >> 6;
    const int l15 = lane & 15, lhi = lane >> 4;
    const int wr = w >> 1, wc = w & 1;

    const int chunk = lane & 7;
    size_t aoff[4], boff[4];
    int ldso[4];
#pragma unroll
    for (int i = 0; i < 4; ++i) {
        int r = w * 32 + i * 8 + (lane >> 3);
        int swz = (chunk * 16) ^ ((r & 7) << 4);
        aoff[i] = ((size_t)(s0 + r)) * 1024 + swz;
        boff[i] = ((size_t)(n0 + r)) * 1024 + swz;
        ldso[i] = (w * 32 + i * 8) * 128;
    }

    f32x4 acc[4][4];
#pragma unroll
    for (int a = 0; a < 4; ++a)
#pragma unroll
        for (int b = 0; b < 4; ++b) acc[a][b] = (f32x4){0.f, 0.f, 0.f, 0.f};

    for (int kb = 0; kb < E_DIM; kb += 64) {
        __syncthreads();
#pragma unroll
        for (int i = 0; i < 4; ++i) {
            size_t ab = aoff[i] + kb * 2;
            size_t bb = boff[i] + kb * 2;
            gl_lds16((const char*)Xhi + ab, (char*)XhS + ldso[i]);
            gl_lds16((const char*)Xlo + ab, (char*)XlS + ldso[i]);
            gl_lds16((const char*)Wh_g + bb, (char*)WhS + ldso[i]);
            gl_lds16((const char*)Wl_g + bb, (char*)WlS + ldso[i]);
        }
        __syncthreads();

#pragma unroll
        for (int kc = 0; kc < 2; ++kc) {
            int cb = kc * 64 + lhi * 16;
            bf16x8 ah[4], al[4], bh[4], bl[4];
#pragma unroll
            for (int rt = 0; rt < 4; ++rt) {
                int row = wr * 64 + rt * 16 + l15;
                int ad = row * 128 + (cb ^ ((row & 7) << 4));
                ah[rt] = *(const bf16x8*)((const char*)XhS + ad);
                al[rt] = *(const bf16x8*)((const char*)XlS + ad);
            }
#pragma unroll
            for (int nt = 0; nt < 4; ++nt) {
                int n = wc * 64 + nt * 16 + l15;
                int bd = n * 128 + (cb ^ ((n & 7) << 4));
                bh[nt] = *(const bf16x8*)((const char*)WhS + bd);
                bl[nt] = *(const bf16x8*)((const char*)WlS + bd);
            }
#pragma unroll
            for (int rt = 0; rt < 4; ++rt)
#pragma unroll
                for (int nt = 0; nt < 4; ++nt) {
                    acc[rt][nt] = mfma16(ah[rt], bh[nt], acc[rt][nt]);
                    acc[rt][nt] = mfma16(ah[rt], bl[nt], acc[rt][nt]);
                    acc[rt][nt] = mfma16(al[rt], bh[nt], acc[rt][nt]);
                }
        }
    }

#pragma unroll
    for (int rt = 0; rt < 4; ++rt)
#pragma unroll
        for (int nt = 0; nt < 4; ++nt) {
            int n = n0 + wc * 64 + nt * 16 + l15;
            int hh = n >> 6, d = n & 63;
#pragma unroll
            for (int j = 0; j < 4; ++j) {
                int s = s0 + wr * 64 + rt * 16 + lhi * 4 + j;
                float val = acc[rt][nt][j];
                size_t o = ((size_t)hh * S_LEN + s) * D_DIM + d;
                if (z == 0) {
                    val *= QSCALE;
                    unsigned short hb = f2bf(val);
                    Qhi[o] = hb;
                    Qlo[o] = f2bf(val - bf2f(hb));
                } else if (z == 1) {
                    unsigned short hb = f2bf(val);
                    Khi[o] = hb;
                    Klo[o] = f2bf(val - bf2f(hb));
                } else {
                    Vb[o] = f2bf(val);
                }
            }
        }
}

// ---------------------------------------------------------------------------
// pack_vt: Vb [h][s][d] bf16 -> Vt [h][d][s] bf16 (LDS tiled transpose)
// ---------------------------------------------------------------------------
__global__ __launch_bounds__(256) void pack_vt(
    const unsigned short* __restrict__ Vb, unsigned short* __restrict__ Vt)
{
    __shared__ unsigned short T[64][72];
    int h = blockIdx.y, sblk = blockIdx.x * 64;
    int t = threadIdx.x;
#pragma unroll
    for (int p = 0; p < 2; ++p) {
        int slot = t + 256 * p;
        int s = slot >> 3, c = slot & 7;
        u16x8 v = *(const u16x8*)&Vb[((size_t)h * S_LEN + sblk + s) * D_DIM + c * 8];
#pragma unroll
        for (int j = 0; j < 8; ++j) T[c * 8 + j][s] = v[j];
    }
    __syncthreads();
#pragma unroll
    for (int p = 0; p < 2; ++p) {
        int slot = t + 256 * p;
        int d = slot >> 3, c = slot & 7;
        u16x8 v;
#pragma unroll
        for (int j = 0; j < 8; ++j) v[j] = T[d][c * 8 + j];
        *(u16x8*)&Vt[((size_t)(h * D_DIM + d)) * S_LEN + sblk + c * 8] = v;
    }
}

// ---------------------------------------------------------------------------
// flash: round-2 proven structure (16x16 MFMA, LDS P round-trip), KSPLIT=4,
// no forced VGPR cap. Block = (64 q-rows, head, ks). 4 waves x 16 rows.
// Scores in exp2 domain (Q pre-scaled). T13 defer-rescale.
// Writes normalized bf16 partials + (m,l) per row.
// ---------------------------------------------------------------------------
__global__ __launch_bounds__(256) void flash_kernel(
    const unsigned short* __restrict__ Qhi, const unsigned short* __restrict__ Qlo,
    const unsigned short* __restrict__ Khi_g, const unsigned short* __restrict__ Klo_g,
    const unsigned short* __restrict__ Vt_g,
    unsigned short* __restrict__ Part, float2* __restrict__ ML)
{
    __shared__ __align__(16) unsigned short KhiS[64 * 64];
    __shared__ __align__(16) unsigned short KloS[64 * 64];
    __shared__ __align__(16) unsigned short VtS[64 * 64];   // [d][key]
    __shared__ __align__(16) unsigned short PS[4][16 * 64]; // per-wave [row][key]

    const int h  = blockIdx.y;
    const int ks = blockIdx.z;
    const int q0 = blockIdx.x * 64;
    const int tid  = threadIdx.x;
    const int lane = tid & 63;
    const int w    = tid >> 6;
    const int l15  = lane & 15;
    const int lhi  = lane >> 4;

    // Q fragments (A-operand): row = l15, d = lhi*8 + 32c + j  [validated r1/r2]
    const int qrow = q0 + w * 16 + l15;
    bf16x8 qh[2], ql[2];
#pragma unroll
    for (int c = 0; c < 2; ++c) {
        size_t off = ((size_t)(h * S_LEN + qrow)) * D_DIM + lhi * 8 + 32 * c;
        qh[c] = *(const bf16x8*)&Qhi[off];
        ql[c] = *(const bf16x8*)&Qlo[off];
    }

    // staging source pointers (pre-swizzled within 128B rows)
    const char *pKh[2], *pKl[2], *pV[2];
    int ldsd[2];
    {
        const int chunk = lane & 7;
#pragma unroll
        for (int i = 0; i < 2; ++i) {
            int r = w * 16 + i * 8 + (lane >> 3);
            int swz = (chunk * 16) ^ ((r & 7) << 4);
            size_t kb = ((size_t)(h * S_LEN + ks * (S_LEN / KSPLIT) + r)) * 128 + swz;
            pKh[i] = (const char*)Khi_g + kb;
            pKl[i] = (const char*)Klo_g + kb;
            size_t vb = ((size_t)(h * D_DIM + r) * S_LEN + ks * (S_LEN / KSPLIT)) * 2 + swz;
            pV[i] = (const char*)Vt_g + vb;
            ldsd[i] = (w * 16 + i * 8) * 128;
        }
    }

    f32x4 acc_o[4];
#pragma unroll
    for (int nt = 0; nt < 4; ++nt) acc_o[nt] = (f32x4){0.f, 0.f, 0.f, 0.f};
    float m2[4], l[4];
#pragma unroll
    for (int r = 0; r < 4; ++r) { m2[r] = -1e30f; l[r] = 0.f; }

    for (int kt = 0; kt < NKT; ++kt) {
        __syncthreads();
#pragma unroll
        for (int i = 0; i < 2; ++i) {
            gl_lds16(pKh[i], (char*)KhiS + ldsd[i]);
            gl_lds16(pKl[i], (char*)KloS + ldsd[i]);
            gl_lds16(pV[i],  (char*)VtS  + ldsd[i]);
            pKh[i] += 8192; pKl[i] += 8192; pV[i] += 128;
        }
        __syncthreads();

        // ---- scores (exp2 domain): 3-term split MFMA
        f32x4 sacc[4];
#pragma unroll
        for (int nt = 0; nt < 4; ++nt) sacc[nt] = (f32x4){0.f, 0.f, 0.f, 0.f};
#pragma unroll
        for (int c = 0; c < 2; ++c) {
            int colb = (lhi * 8 + 32 * c) * 2;
#pragma unroll
            for (int nt = 0; nt < 4; ++nt) {
                int key = l15 + 16 * nt;
                int lo = key * 128 + (((colb >> 4) ^ (key & 7)) << 4);
                bf16x8 kh = *(const bf16x8*)((const char*)KhiS + lo);
                bf16x8 kl = *(const bf16x8*)((const char*)KloS + lo);
                sacc[nt] = mfma16(qh[c], kh, sacc[nt]);
                sacc[nt] = mfma16(qh[c], kl, sacc[nt]);
                sacc[nt] = mfma16(ql[c], kh, sacc[nt]);
            }
        }

        // ---- online softmax, T13 defer-rescale (p bounded by 2^8)
        float p[4][4];
#pragma unroll
        for (int r = 0; r < 4; ++r) {
            float vm = fmaxf(fmaxf(sacc[0][r], sacc[1][r]), fmaxf(sacc[2][r], sacc[3][r]));
#pragma unroll
            for (int off = 1; off < 16; off <<= 1) vm = fmaxf(vm, __shfl_xor(vm, off));
            if (vm > m2[r] + 8.f) {
                float sc = exp2f(m2[r] - vm);
                m2[r] = vm;
                l[r] *= sc;
#pragma unroll
                for (int nt = 0; nt < 4; ++nt) acc_o[nt][r] *= sc;
            }
            float sum = 0.f;
#pragma unroll
            for (int nt = 0; nt < 4; ++nt) {
                float pv = exp2f(sacc[nt][r] - m2[r]);
                p[nt][r] = pv;
                sum += pv;
            }
#pragma unroll
            for (int off = 1; off < 16; off <<= 1) sum += __shfl_xor(sum, off);
            l[r] += sum;
        }

        // ---- P -> per-wave LDS (row = q-row 0..15, col = key, swizzled)
        unsigned short* pw = &PS[w][0];
#pragma unroll
        for (int nt = 0; nt < 4; ++nt) {
            int colb = (l15 + 16 * nt) * 2;
#pragma unroll
            for (int r = 0; r < 4; ++r) {
                int row = lhi * 4 + r;
                int lo = row * 128 + (((colb >> 4) ^ (row & 7)) << 4) + (colb & 15);
                *(unsigned short*)((char*)pw + lo) = f2bf(p[nt][r]);
            }
        }

        // ---- PV
#pragma unroll
        for (int c = 0; c < 2; ++c) {
            int colb = (lhi * 8 + 32 * c) * 2;
            int loA = l15 * 128 + (((colb >> 4) ^ (l15 & 7)) << 4);
            bf16x8 pa = *(const bf16x8*)((const char*)pw + loA);
#pragma unroll
            for (int nt = 0; nt < 4; ++nt) {
                int d = l15 + 16 * nt;
                int loB = d * 128 + (((colb >> 4) ^ (d & 7)) << 4);
                bf16x8 vb = *(const bf16x8*)((const char*)VtS + loB);
                acc_o[nt] = mfma16(pa, vb, acc_o[nt]);
            }
        }
    }

    // ---- epilogue: normalized bf16 partial + (m,l)
    unsigned short* PT = Part + ((size_t)(ks * H_NUM + h)) * S_LEN * D_DIM;
#pragma unroll
    for (int r = 0; r < 4; ++r) {
        float inv = 1.f / l[r];
        int s = q0 + w * 16 + lhi * 4 + r;
#pragma unroll
        for (int nt = 0; nt < 4; ++nt)
            PT[(size_t)s * D_DIM + l15 + 16 * nt] = f2bf(acc_o[nt][r] * inv);
        if (l15 == 0)
            ML[(size_t)(ks * H_NUM + h) * S_LEN + s] = make_float2(m2[r], l[r]);
    }
}

// ---------------------------------------------------------------------------
// cw: per (h,s) combine weights c_i = l_i*2^(m_i-m) / L  (4 splits)
// ---------------------------------------------------------------------------
__global__ __launch_bounds__(256) void cw_kernel(
    const float2* __restrict__ ML, float4* __restrict__ CW)
{
    int i = blockIdx.x * 256 + threadIdx.x;   // H*S = 32768
    float2 a[KSPLIT];
    float m = -1e30f;
#pragma unroll
    for (int k = 0; k < KSPLIT; ++k) {
        a[k] = ML[(size_t)k * H_NUM * S_LEN + i];
        m = fmaxf(m, a[k].x);
    }
    float wk[KSPLIT], wsum = 0.f;
#pragma unroll
    for (int k = 0; k < KSPLIT; ++k) {
        wk[k] = exp2f(a[k].x - m) * a[k].y;
        wsum += wk[k];
    }
    float inv = 1.f / wsum;
    CW[i] = make_float4(wk[0] * inv, wk[1] * inv, wk[2] * inv, wk[3] * inv);
}

// ---------------------------------------------------------------------------
// zout: Z[4096,64] = combine(4 partials) [4096,512] @ W0[512,64], fp32.
// ---------------------------------------------------------------------------
__global__ __launch_bounds__(256) void zout_kernel(
    const unsigned short* __restrict__ Part, const float4* __restrict__ CW,
    const float* __restrict__ W0, float* __restrict__ Z)
{
    __shared__ __align__(16) float Rs[32][64];
    __shared__ __align__(16) float Ws[32][64];

    const size_t PSZ = (size_t)H_NUM * S_LEN * D_DIM;
    const int s0 = blockIdx.x * 64;
    const int tid = threadIdx.x;
    const int tx = tid & 15;
    const int ty = tid >> 4;

    float acc[4][4];
#pragma unroll
    for (int i = 0; i < 4; ++i)
#pragma unroll
        for (int j = 0; j < 4; ++j) acc[i][j] = 0.f;

    for (int kb = 0; kb < E_DIM; kb += 32) {
        __syncthreads();
#pragma unroll
        for (int p = 0; p < 2; ++p) {
            int idx = tid + 256 * p;
            int row = idx >> 3;
            int kq  = idx & 7;
            int k = kb + kq * 4;
            int hh = k >> 6, d0 = k & 63;
            int s = s0 + row;
            size_t pbase = ((size_t)hh * S_LEN + s) * D_DIM + d0;
            float4 c = *(const float4*)&CW[hh * S_LEN + s];
            u16x4 a0 = *(const u16x4*)&Part[pbase];
            u16x4 a1 = *(const u16x4*)&Part[PSZ + pbase];
            u16x4 a2 = *(const u16x4*)&Part[2 * PSZ + pbase];
            u16x4 a3 = *(const u16x4*)&Part[3 * PSZ + pbase];
#pragma unroll
            for (int j = 0; j < 4; ++j)
                Rs[kq * 4 + j][row] = bf2f(a0[j]) * c.x + bf2f(a1[j]) * c.y +
                                      bf2f(a2[j]) * c.z + bf2f(a3[j]) * c.w;
        }
#pragma unroll
        for (int p = 0; p < 2; ++p) {
            int idx = tid + 256 * p;
            int k  = idx >> 4;
            int nq = idx & 15;
            *(float4*)&Ws[k][nq * 4] = *(const float4*)&W0[(size_t)(kb + k) * D_DIM + nq * 4];
        }
        __syncthreads();

#pragma unroll 8
        for (int k = 0; k < 32; ++k) {
            float a[4], b[4];
            *(float4*)&a[0] = *(const float4*)&Rs[k][ty * 4];
            *(float4*)&b[0] = *(const float4*)&Ws[k][tx * 4];
#pragma unroll
            for (int i = 0; i < 4; ++i)
#pragma unroll
                for (int j = 0; j < 4; ++j) acc[i][j] += a[i] * b[j];
        }
    }

#pragma unroll
    for (int i = 0; i < 4; ++i) {
        float4 o = make_float4(acc[i][0], acc[i][1], acc[i][2], acc[i][3]);
        *(float4*)&Z[(size_t)(s0 + ty * 4 + i) * D_DIM + tx * 4] = o;
    }
}

// ---------------------------------------------------------------------------
extern "C" void kernel_launch(void* const* d_in, const int* in_sizes, int n_in,
                              void* d_out, int out_size, void* d_ws, size_t ws_size,
                              hipStream_t stream) {
    const float* X  = (const float*)d_in[0];
    const float* Wq = (const float*)d_in[1];
    const float* Wk = (const float*)d_in[2];
    const float* Wv = (const float*)d_in[3];
    const float* W0 = (const float*)d_in[4];

    char* ws = (char*)d_ws;
    const size_t MB = 1ull << 20;
    unsigned short* Qhi = (unsigned short*)(ws + 0 * MB);
    unsigned short* Qlo = (unsigned short*)(ws + 4 * MB);
    unsigned short* Khi = (unsigned short*)(ws + 8 * MB);
    unsigned short* Klo = (unsigned short*)(ws + 12 * MB);
    unsigned short* Vt  = (unsigned short*)(ws + 16 * MB);
    // phase-1 region (dead before flash writes Part):
    unsigned short* Vb  = (unsigned short*)(ws + 20 * MB);   // aliases Part[0:4MB]
    unsigned short* Xhi = (unsigned short*)(ws + 24 * MB);
    unsigned short* Xlo = (unsigned short*)(ws + 28 * MB);
    unsigned short* WT  = (unsigned short*)(ws + 32 * MB);   // 3 MB
    // phase-2:
    unsigned short* Part = (unsigned short*)(ws + 20 * MB);  // 16 MB (4 splits)
    float2* ML = (float2*)(ws + 36 * MB);                    // 1 MB
    float4* CW = (float4*)(ws + 37 * MB);                    // 0.5 MB

    float* Z = (float*)d_out;

    prepass_x<<<dim3(S_LEN * E_DIM / 4 / 256), 256, 0, stream>>>(X, Xhi, Xlo);
    prepass_w<<<dim3(E_DIM * 128 / 256, 3), 256, 0, stream>>>(Wq, Wk, Wv, WT);
    proj_kernel<<<dim3(S_LEN / 128, 4, 3), 256, 0, stream>>>(
        Xhi, Xlo, WT, Qhi, Qlo, Khi, Klo, Vb);
    pack_vt<<<dim3(S_LEN / 64, H_NUM), 256, 0, stream>>>(Vb, Vt);
    flash_kernel<<<dim3(S_LEN / 64, H_NUM, KSPLIT), 256, 0, stream>>>(
        Qhi, Qlo, Khi, Klo, Vt, Part, ML);
    cw_kernel<<<dim3(H_NUM * S_LEN / 256), 256, 0, stream>>>(ML, CW);
    zout_kernel<<<dim3(S_LEN / 64), 256, 0, stream>>>(Part, CW, W0, Z);
}

// Round 6
// 228.245 us; speedup vs baseline: 1.6256x; 1.2265x over previous
//
#include <hip/hip_runtime.h>
#include <hip/hip_bf16.h>

#define S_LEN 4096
#define E_DIM 512
#define D_DIM 64
#define H_NUM 8
#define KSPLIT 4
#define NKT ((S_LEN / KSPLIT) / 64)   // 16 key tiles per flash block
// scale = 1/sqrt(64) * log2(e): scores come out of MFMA already in exp2 domain
#define QSCALE 0.18033688011112042f

typedef short bf16x8 __attribute__((ext_vector_type(8)));
typedef float f32x4 __attribute__((ext_vector_type(4)));
typedef unsigned short u16x8 __attribute__((ext_vector_type(8)));
typedef unsigned short u16x4 __attribute__((ext_vector_type(4)));

__device__ inline unsigned short f2bf(float x) {
    union { float f; unsigned u; } v; v.f = x;
    unsigned r = v.u + 0x7FFFu + ((v.u >> 16) & 1u);
    return (unsigned short)(r >> 16);
}
__device__ inline float bf2f(unsigned short b) {
    union { unsigned u; float f; } v; v.u = ((unsigned)b) << 16;
    return v.f;
}
__device__ inline f32x4 mfma16(bf16x8 a, bf16x8 b, f32x4 c) {
    return __builtin_amdgcn_mfma_f32_16x16x32_bf16(a, b, c, 0, 0, 0);
}
__device__ inline void gl_lds16(const void* g, void* l) {
    __builtin_amdgcn_global_load_lds(
        (const __attribute__((address_space(1))) void*)g,
        (__attribute__((address_space(3))) void*)l, 16, 0, 0);
}
// dst = {bf16(a) lo16, bf16(b) hi16}
__device__ inline unsigned cvtpk(float a, float b) {
    unsigned r;
    asm volatile("v_cvt_pk_bf16_f32 %0, %1, %2" : "=v"(r) : "v"(a), "v"(b));
    return r;
}

// ---------------------------------------------------------------------------
// prepass_x: X fp32 [4096,512] -> Xhi,Xlo bf16 (hi/lo split)
// ---------------------------------------------------------------------------
__global__ __launch_bounds__(256) void prepass_x(
    const float* __restrict__ X, unsigned short* __restrict__ Xhi,
    unsigned short* __restrict__ Xlo)
{
    int i = (blockIdx.x * 256 + threadIdx.x) * 4;
    float4 v = *(const float4*)&X[i];
    float a[4] = {v.x, v.y, v.z, v.w};
    u16x4 hv, lv;
#pragma unroll
    for (int j = 0; j < 4; ++j) {
        unsigned short hb = f2bf(a[j]);
        hv[j] = hb;
        lv[j] = f2bf(a[j] - bf2f(hb));
    }
    *(u16x4*)&Xhi[i] = hv;
    *(u16x4*)&Xlo[i] = lv;
}

// ---------------------------------------------------------------------------
// prepass_w: W_z [H,E,D] fp32 -> WT[z][hl][n=h*64+d][e] bf16 hi/lo (transposed)
// ---------------------------------------------------------------------------
__global__ __launch_bounds__(256) void prepass_w(
    const float* __restrict__ Wq, const float* __restrict__ Wk,
    const float* __restrict__ Wv, unsigned short* __restrict__ WT)
{
    int z = blockIdx.y;
    const float* W = (z == 0) ? Wq : (z == 1) ? Wk : Wv;
    int idx = blockIdx.x * 256 + threadIdx.x;        // 512*128
    int n = idx >> 7;
    int e = (idx & 127) * 4;
    int hh = n >> 6, d = n & 63;
    unsigned short* Whi = WT + (size_t)z * 2 * 262144;
    unsigned short* Wlo = Whi + 262144;
    u16x4 hv, lv;
#pragma unroll
    for (int j = 0; j < 4; ++j) {
        float v = W[((size_t)hh * E_DIM + e + j) * D_DIM + d];
        unsigned short hb = f2bf(v);
        hv[j] = hb;
        lv[j] = f2bf(v - bf2f(hb));
    }
    *(u16x4*)&Whi[(size_t)n * E_DIM + e] = hv;
    *(u16x4*)&Wlo[(size_t)n * E_DIM + e] = lv;
}

// ---------------------------------------------------------------------------
// proj: C[4096,512] = X @ Wcat per z, 3-term split-bf16 MFMA (fp32-accurate).
// ---------------------------------------------------------------------------
__global__ __launch_bounds__(256) void proj_kernel(
    const unsigned short* __restrict__ Xhi, const unsigned short* __restrict__ Xlo,
    const unsigned short* __restrict__ WT,
    unsigned short* __restrict__ Qhi, unsigned short* __restrict__ Qlo,
    unsigned short* __restrict__ Khi, unsigned short* __restrict__ Klo,
    unsigned short* __restrict__ Vb)
{
    __shared__ __align__(16) unsigned short XhS[128 * 64];
    __shared__ __align__(16) unsigned short XlS[128 * 64];
    __shared__ __align__(16) unsigned short WhS[128 * 64];
    __shared__ __align__(16) unsigned short WlS[128 * 64];

    const int s0 = blockIdx.x * 128, n0 = blockIdx.y * 128, z = blockIdx.z;
    const unsigned short* Wh_g = WT + (size_t)z * 524288;
    const unsigned short* Wl_g = Wh_g + 262144;

    const int tid = threadIdx.x, lane = tid & 63, w = tid >> 6;
    const int l15 = lane & 15, lhi = lane >> 4;
    const int wr = w >> 1, wc = w & 1;

    const int chunk = lane & 7;
    size_t aoff[4], boff[4];
    int ldso[4];
#pragma unroll
    for (int i = 0; i < 4; ++i) {
        int r = w * 32 + i * 8 + (lane >> 3);
        int swz = (chunk * 16) ^ ((r & 7) << 4);
        aoff[i] = ((size_t)(s0 + r)) * 1024 + swz;
        boff[i] = ((size_t)(n0 + r)) * 1024 + swz;
        ldso[i] = (w * 32 + i * 8) * 128;
    }

    f32x4 acc[4][4];
#pragma unroll
    for (int a = 0; a < 4; ++a)
#pragma unroll
        for (int b = 0; b < 4; ++b) acc[a][b] = (f32x4){0.f, 0.f, 0.f, 0.f};

    for (int kb = 0; kb < E_DIM; kb += 64) {
        __syncthreads();
#pragma unroll
        for (int i = 0; i < 4; ++i) {
            size_t ab = aoff[i] + kb * 2;
            size_t bb = boff[i] + kb * 2;
            gl_lds16((const char*)Xhi + ab, (char*)XhS + ldso[i]);
            gl_lds16((const char*)Xlo + ab, (char*)XlS + ldso[i]);
            gl_lds16((const char*)Wh_g + bb, (char*)WhS + ldso[i]);
            gl_lds16((const char*)Wl_g + bb, (char*)WlS + ldso[i]);
        }
        __syncthreads();

#pragma unroll
        for (int kc = 0; kc < 2; ++kc) {
            int cb = kc * 64 + lhi * 16;
            bf16x8 ah[4], al[4], bh[4], bl[4];
#pragma unroll
            for (int rt = 0; rt < 4; ++rt) {
                int row = wr * 64 + rt * 16 + l15;
                int ad = row * 128 + (cb ^ ((row & 7) << 4));
                ah[rt] = *(const bf16x8*)((const char*)XhS + ad);
                al[rt] = *(const bf16x8*)((const char*)XlS + ad);
            }
#pragma unroll
            for (int nt = 0; nt < 4; ++nt) {
                int n = wc * 64 + nt * 16 + l15;
                int bd = n * 128 + (cb ^ ((n & 7) << 4));
                bh[nt] = *(const bf16x8*)((const char*)WhS + bd);
                bl[nt] = *(const bf16x8*)((const char*)WlS + bd);
            }
#pragma unroll
            for (int rt = 0; rt < 4; ++rt)
#pragma unroll
                for (int nt = 0; nt < 4; ++nt) {
                    acc[rt][nt] = mfma16(ah[rt], bh[nt], acc[rt][nt]);
                    acc[rt][nt] = mfma16(ah[rt], bl[nt], acc[rt][nt]);
                    acc[rt][nt] = mfma16(al[rt], bh[nt], acc[rt][nt]);
                }
        }
    }

#pragma unroll
    for (int rt = 0; rt < 4; ++rt)
#pragma unroll
        for (int nt = 0; nt < 4; ++nt) {
            int n = n0 + wc * 64 + nt * 16 + l15;
            int hh = n >> 6, d = n & 63;
#pragma unroll
            for (int j = 0; j < 4; ++j) {
                int s = s0 + wr * 64 + rt * 16 + lhi * 4 + j;
                float val = acc[rt][nt][j];
                size_t o = ((size_t)hh * S_LEN + s) * D_DIM + d;
                if (z == 0) {
                    val *= QSCALE;
                    unsigned short hb = f2bf(val);
                    Qhi[o] = hb;
                    Qlo[o] = f2bf(val - bf2f(hb));
                } else if (z == 1) {
                    unsigned short hb = f2bf(val);
                    Khi[o] = hb;
                    Klo[o] = f2bf(val - bf2f(hb));
                } else {
                    Vb[o] = f2bf(val);
                }
            }
        }
}

// ---------------------------------------------------------------------------
// pack_vt: Vb [h][s][d] bf16 -> Vt [h][d][s] bf16 (LDS tiled transpose)
// ---------------------------------------------------------------------------
__global__ __launch_bounds__(256) void pack_vt(
    const unsigned short* __restrict__ Vb, unsigned short* __restrict__ Vt)
{
    __shared__ unsigned short T[64][72];
    int h = blockIdx.y, sblk = blockIdx.x * 64;
    int t = threadIdx.x;
#pragma unroll
    for (int p = 0; p < 2; ++p) {
        int slot = t + 256 * p;
        int s = slot >> 3, c = slot & 7;
        u16x8 v = *(const u16x8*)&Vb[((size_t)h * S_LEN + sblk + s) * D_DIM + c * 8];
#pragma unroll
        for (int j = 0; j < 8; ++j) T[c * 8 + j][s] = v[j];
    }
    __syncthreads();
#pragma unroll
    for (int p = 0; p < 2; ++p) {
        int slot = t + 256 * p;
        int d = slot >> 3, c = slot & 7;
        u16x8 v;
#pragma unroll
        for (int j = 0; j < 8; ++j) v[j] = T[d][c * 8 + j];
        *(u16x8*)&Vt[((size_t)(h * D_DIM + d)) * S_LEN + sblk + c * 8] = v;
    }
}

// ---------------------------------------------------------------------------
// flash: SWAPPED QK^T (A=K, B=Q) at 16x16 — same proven fragment layouts and
// LDS addresses as r5, only the mfma operand order changes. Each lane's 16
// scores all belong to q-row l15 -> in-lane softmax (2 shfl vs 32), P-repack
// via 8 cvt_pk + 4 ds_write_b64 (vs 16 f2bf + 16 b16 writes).
// sacc[nt][j] = S[key = 16nt + lhi*4 + j][q = l15].
// ---------------------------------------------------------------------------
__global__ __launch_bounds__(256) void flash_kernel(
    const unsigned short* __restrict__ Qhi, const unsigned short* __restrict__ Qlo,
    const unsigned short* __restrict__ Khi_g, const unsigned short* __restrict__ Klo_g,
    const unsigned short* __restrict__ Vt_g,
    unsigned short* __restrict__ Part, float2* __restrict__ ML)
{
    __shared__ __align__(16) unsigned short KhiS[64 * 64];
    __shared__ __align__(16) unsigned short KloS[64 * 64];
    __shared__ __align__(16) unsigned short VtS[64 * 64];   // [d][key]
    __shared__ __align__(16) unsigned short PS[4][16 * 64]; // per-wave [row][key]

    const int h  = blockIdx.y;
    const int ks = blockIdx.z;
    const int q0 = blockIdx.x * 64;
    const int tid  = threadIdx.x;
    const int lane = tid & 63;
    const int w    = tid >> 6;
    const int l15  = lane & 15;
    const int lhi  = lane >> 4;

    // Q fragments (B-operand now): col = l15 = qrow, k(d) = lhi*8 + 32c + j
    // — identical addresses to r5's A-operand load (validated).
    const int qrow = q0 + w * 16 + l15;
    bf16x8 qh[2], ql[2];
#pragma unroll
    for (int c = 0; c < 2; ++c) {
        size_t off = ((size_t)(h * S_LEN + qrow)) * D_DIM + lhi * 8 + 32 * c;
        qh[c] = *(const bf16x8*)&Qhi[off];
        ql[c] = *(const bf16x8*)&Qlo[off];
    }

    // staging source pointers (pre-swizzled within 128B rows)
    const char *pKh[2], *pKl[2], *pV[2];
    int ldsd[2];
    {
        const int chunk = lane & 7;
#pragma unroll
        for (int i = 0; i < 2; ++i) {
            int r = w * 16 + i * 8 + (lane >> 3);
            int swz = (chunk * 16) ^ ((r & 7) << 4);
            size_t kb = ((size_t)(h * S_LEN + ks * (S_LEN / KSPLIT) + r)) * 128 + swz;
            pKh[i] = (const char*)Khi_g + kb;
            pKl[i] = (const char*)Klo_g + kb;
            size_t vb = ((size_t)(h * D_DIM + r) * S_LEN + ks * (S_LEN / KSPLIT)) * 2 + swz;
            pV[i] = (const char*)Vt_g + vb;
            ldsd[i] = (w * 16 + i * 8) * 128;
        }
    }

    f32x4 acc_o[4];
#pragma unroll
    for (int nt = 0; nt < 4; ++nt) acc_o[nt] = (f32x4){0.f, 0.f, 0.f, 0.f};
    float m2 = -1e30f, lsum = 0.f;   // state for q-row l15 (replicated over lhi)

    unsigned short* pw = &PS[w][0];

    for (int kt = 0; kt < NKT; ++kt) {
        __syncthreads();
#pragma unroll
        for (int i = 0; i < 2; ++i) {
            gl_lds16(pKh[i], (char*)KhiS + ldsd[i]);
            gl_lds16(pKl[i], (char*)KloS + ldsd[i]);
            gl_lds16(pV[i],  (char*)VtS  + ldsd[i]);
            pKh[i] += 8192; pKl[i] += 8192; pV[i] += 128;
        }
        __syncthreads();

        // ---- scores (exp2 domain): 3-term split MFMA, swapped (A=K, B=Q)
        f32x4 sacc[4];
#pragma unroll
        for (int nt = 0; nt < 4; ++nt) sacc[nt] = (f32x4){0.f, 0.f, 0.f, 0.f};
#pragma unroll
        for (int c = 0; c < 2; ++c) {
            int colb = (lhi * 8 + 32 * c) * 2;
#pragma unroll
            for (int nt = 0; nt < 4; ++nt) {
                int key = l15 + 16 * nt;      // A row = key within tile
                int lo = key * 128 + (((colb >> 4) ^ (key & 7)) << 4);
                bf16x8 kh = *(const bf16x8*)((const char*)KhiS + lo);
                bf16x8 kl = *(const bf16x8*)((const char*)KloS + lo);
                sacc[nt] = mfma16(kh, qh[c], sacc[nt]);
                sacc[nt] = mfma16(kl, qh[c], sacc[nt]);
                sacc[nt] = mfma16(kh, ql[c], sacc[nt]);
            }
        }

        // ---- softmax for q-row l15 (16 in-lane scores + 2 shfl)
        float mx0 = fmaxf(fmaxf(sacc[0][0], sacc[0][1]), fmaxf(sacc[0][2], sacc[0][3]));
        float mx1 = fmaxf(fmaxf(sacc[1][0], sacc[1][1]), fmaxf(sacc[1][2], sacc[1][3]));
        float mx2 = fmaxf(fmaxf(sacc[2][0], sacc[2][1]), fmaxf(sacc[2][2], sacc[2][3]));
        float mx3 = fmaxf(fmaxf(sacc[3][0], sacc[3][1]), fmaxf(sacc[3][2], sacc[3][3]));
        float vm = fmaxf(fmaxf(mx0, mx1), fmaxf(mx2, mx3));
        vm = fmaxf(vm, __shfl_xor(vm, 16));
        vm = fmaxf(vm, __shfl_xor(vm, 32));

        // T13 defer-rescale: only rescale when some row's max grew by > 8
        if (!__all(vm <= m2 + 8.f)) {
            float mnew = fmaxf(m2, vm);
            float sc = exp2f(m2 - mnew);
            m2 = mnew;
            lsum *= sc;
            float scj[4];
#pragma unroll
            for (int j = 0; j < 4; ++j) scj[j] = __shfl(sc, lhi * 4 + j);
#pragma unroll
            for (int nt = 0; nt < 4; ++nt)
#pragma unroll
                for (int j = 0; j < 4; ++j) acc_o[nt][j] *= scj[j];
        }

        // ---- e = exp2(s - m2); pack pairs; write 8B per nt (keys 16nt+lhi*4..+4)
        float sum = 0.f;
#pragma unroll
        for (int nt = 0; nt < 4; ++nt) {
            float e0 = exp2f(sacc[nt][0] - m2);
            float e1 = exp2f(sacc[nt][1] - m2);
            float e2 = exp2f(sacc[nt][2] - m2);
            float e3 = exp2f(sacc[nt][3] - m2);
            sum += (e0 + e1) + (e2 + e3);
            int colb = 32 * nt + 8 * lhi;
            int adr = l15 * 128 + ((((colb >> 4)) ^ (l15 & 7)) << 4) + (colb & 15);
            uint2 pk = make_uint2(cvtpk(e0, e1), cvtpk(e2, e3));
            *(uint2*)((char*)pw + adr) = pk;
        }
        sum += __shfl_xor(sum, 16);
        sum += __shfl_xor(sum, 32);
        lsum += sum;

        // ---- PV: A = P[row=l15][k=key], B = V^T[col=d][k=key]  (unchanged)
#pragma unroll
        for (int c = 0; c < 2; ++c) {
            int colb = (lhi * 8 + 32 * c) * 2;
            int loA = l15 * 128 + (((colb >> 4) ^ (l15 & 7)) << 4);
            bf16x8 pa = *(const bf16x8*)((const char*)pw + loA);
#pragma unroll
            for (int nt = 0; nt < 4; ++nt) {
                int d = l15 + 16 * nt;
                int loB = d * 128 + (((colb >> 4) ^ (d & 7)) << 4);
                bf16x8 vb = *(const bf16x8*)((const char*)VtS + loB);
                acc_o[nt] = mfma16(pa, vb, acc_o[nt]);
            }
        }
    }

    // ---- epilogue: normalized bf16 partial + (m,l)
    if (lane < 16) {
        ML[(size_t)(ks * H_NUM + h) * S_LEN + q0 + w * 16 + l15] =
            make_float2(m2, lsum);
    }
    unsigned short* PT = Part + ((size_t)(ks * H_NUM + h)) * S_LEN * D_DIM;
#pragma unroll
    for (int r = 0; r < 4; ++r) {
        float lr = __shfl(lsum, lhi * 4 + r);
        float inv = 1.f / lr;
        int s = q0 + w * 16 + lhi * 4 + r;
#pragma unroll
        for (int nt = 0; nt < 4; ++nt)
            PT[(size_t)s * D_DIM + l15 + 16 * nt] = f2bf(acc_o[nt][r] * inv);
    }
}

// ---------------------------------------------------------------------------
// cw: per (h,s) combine weights c_i = l_i*2^(m_i-m) / L  (4 splits)
// ---------------------------------------------------------------------------
__global__ __launch_bounds__(256) void cw_kernel(
    const float2* __restrict__ ML, float4* __restrict__ CW)
{
    int i = blockIdx.x * 256 + threadIdx.x;   // H*S = 32768
    float2 a[KSPLIT];
    float m = -1e30f;
#pragma unroll
    for (int k = 0; k < KSPLIT; ++k) {
        a[k] = ML[(size_t)k * H_NUM * S_LEN + i];
        m = fmaxf(m, a[k].x);
    }
    float wk[KSPLIT], wsum = 0.f;
#pragma unroll
    for (int k = 0; k < KSPLIT; ++k) {
        wk[k] = exp2f(a[k].x - m) * a[k].y;
        wsum += wk[k];
    }
    float inv = 1.f / wsum;
    CW[i] = make_float4(wk[0] * inv, wk[1] * inv, wk[2] * inv, wk[3] * inv);
}

// ---------------------------------------------------------------------------
// zout: Z[4096,64] = combine(4 partials) [4096,512] @ W0[512,64], fp32.
// ---------------------------------------------------------------------------
__global__ __launch_bounds__(256) void zout_kernel(
    const unsigned short* __restrict__ Part, const float4* __restrict__ CW,
    const float* __restrict__ W0, float* __restrict__ Z)
{
    __shared__ __align__(16) float Rs[32][64];
    __shared__ __align__(16) float Ws[32][64];

    const size_t PSZ = (size_t)H_NUM * S_LEN * D_DIM;
    const int s0 = blockIdx.x * 64;
    const int tid = threadIdx.x;
    const int tx = tid & 15;
    const int ty = tid >> 4;

    float acc[4][4];
#pragma unroll
    for (int i = 0; i < 4; ++i)
#pragma unroll
        for (int j = 0; j < 4; ++j) acc[i][j] = 0.f;

    for (int kb = 0; kb < E_DIM; kb += 32) {
        __syncthreads();
#pragma unroll
        for (int p = 0; p < 2; ++p) {
            int idx = tid + 256 * p;
            int row = idx >> 3;
            int kq  = idx & 7;
            int k = kb + kq * 4;
            int hh = k >> 6, d0 = k & 63;
            int s = s0 + row;
            size_t pbase = ((size_t)hh * S_LEN + s) * D_DIM + d0;
            float4 c = *(const float4*)&CW[hh * S_LEN + s];
            u16x4 a0 = *(const u16x4*)&Part[pbase];
            u16x4 a1 = *(const u16x4*)&Part[PSZ + pbase];
            u16x4 a2 = *(const u16x4*)&Part[2 * PSZ + pbase];
            u16x4 a3 = *(const u16x4*)&Part[3 * PSZ + pbase];
#pragma unroll
            for (int j = 0; j < 4; ++j)
                Rs[kq * 4 + j][row] = bf2f(a0[j]) * c.x + bf2f(a1[j]) * c.y +
                                      bf2f(a2[j]) * c.z + bf2f(a3[j]) * c.w;
        }
#pragma unroll
        for (int p = 0; p < 2; ++p) {
            int idx = tid + 256 * p;
            int k  = idx >> 4;
            int nq = idx & 15;
            *(float4*)&Ws[k][nq * 4] = *(const float4*)&W0[(size_t)(kb + k) * D_DIM + nq * 4];
        }
        __syncthreads();

#pragma unroll 8
        for (int k = 0; k < 32; ++k) {
            float a[4], b[4];
            *(float4*)&a[0] = *(const float4*)&Rs[k][ty * 4];
            *(float4*)&b[0] = *(const float4*)&Ws[k][tx * 4];
#pragma unroll
            for (int i = 0; i < 4; ++i)
#pragma unroll
                for (int j = 0; j < 4; ++j) acc[i][j] += a[i] * b[j];
        }
    }

#pragma unroll
    for (int i = 0; i < 4; ++i) {
        float4 o = make_float4(acc[i][0], acc[i][1], acc[i][2], acc[i][3]);
        *(float4*)&Z[(size_t)(s0 + ty * 4 + i) * D_DIM + tx * 4] = o;
    }
}

// ---------------------------------------------------------------------------
extern "C" void kernel_launch(void* const* d_in, const int* in_sizes, int n_in,
                              void* d_out, int out_size, void* d_ws, size_t ws_size,
                              hipStream_t stream) {
    const float* X  = (const float*)d_in[0];
    const float* Wq = (const float*)d_in[1];
    const float* Wk = (const float*)d_in[2];
    const float* Wv = (const float*)d_in[3];
    const float* W0 = (const float*)d_in[4];

    char* ws = (char*)d_ws;
    const size_t MB = 1ull << 20;
    unsigned short* Qhi = (unsigned short*)(ws + 0 * MB);
    unsigned short* Qlo = (unsigned short*)(ws + 4 * MB);
    unsigned short* Khi = (unsigned short*)(ws + 8 * MB);
    unsigned short* Klo = (unsigned short*)(ws + 12 * MB);
    unsigned short* Vt  = (unsigned short*)(ws + 16 * MB);
    // phase-1 region (dead before flash writes Part):
    unsigned short* Vb  = (unsigned short*)(ws + 20 * MB);   // aliases Part[0:4MB]
    unsigned short* Xhi = (unsigned short*)(ws + 24 * MB);
    unsigned short* Xlo = (unsigned short*)(ws + 28 * MB);
    unsigned short* WT  = (unsigned short*)(ws + 32 * MB);   // 3 MB
    // phase-2:
    unsigned short* Part = (unsigned short*)(ws + 20 * MB);  // 16 MB (4 splits)
    float2* ML = (float2*)(ws + 36 * MB);                    // 1 MB
    float4* CW = (float4*)(ws + 37 * MB);                    // 0.5 MB

    float* Z = (float*)d_out;

    prepass_x<<<dim3(S_LEN * E_DIM / 4 / 256), 256, 0, stream>>>(X, Xhi, Xlo);
    prepass_w<<<dim3(E_DIM * 128 / 256, 3), 256, 0, stream>>>(Wq, Wk, Wv, WT);
    proj_kernel<<<dim3(S_LEN / 128, 4, 3), 256, 0, stream>>>(
        Xhi, Xlo, WT, Qhi, Qlo, Khi, Klo, Vb);
    pack_vt<<<dim3(S_LEN / 64, H_NUM), 256, 0, stream>>>(Vb, Vt);
    flash_kernel<<<dim3(S_LEN / 64, H_NUM, KSPLIT), 256, 0, stream>>>(
        Qhi, Qlo, Khi, Klo, Vt, Part, ML);
    cw_kernel<<<dim3(H_NUM * S_LEN / 256), 256, 0, stream>>>(ML, CW);
    zout_kernel<<<dim3(S_LEN / 64), 256, 0, stream>>>(Part, CW, W0, Z);
}